// Round 4
// baseline (469.307 us; speedup 1.0000x reference)
//
#include <hip/hip_runtime.h>

// Problem: B=16, T=2048, D=512, H=512, K=2
// M = B*T = 32768, GEMM-K = 1024, N = 3H = 1536.
//
// ws layout (bytes):
//   Xpad [16][2049][512] bf16 @ 0         (33,570,816)  row 0 of each batch = 0
//                                          (dead after gemm; P/C/I overlay it)
//   Bbf  [1536][1024] bf16 @ 33570816     ( 3,145,728)
//   GT   [1536][32768] bf16 @ 36716544    (100,663,296) pre-activation, transposed

#define MTOT 32768
#define NTOT 1536
#define KTOT 1024
#define DCH  512
#define TLEN 2048
#define NB   16

// scan decomposition: SC chunks of LC steps per (b,h) chain; LC*2B = one 128B line
#define SC 32
#define LC 64

typedef __bf16 bf16x8 __attribute__((ext_vector_type(8)));
typedef float  f32x4  __attribute__((ext_vector_type(4)));

__device__ __forceinline__ unsigned short f2bf(float x) {
    unsigned u = __float_as_uint(x);
    u += 0x7FFFu + ((u >> 16) & 1u);   // RNE
    return (unsigned short)(u >> 16);
}
__device__ __forceinline__ float sigmoidf_(float x) {
    return 1.f / (1.f + __expf(-x));
}

// ---------------------------------------------------------------------------
// K0: Xpad[b][r][d] = (r==0) ? 0 : bf16(in[b][r-1][d]).  grid (513,16), 4 rows/blk
__global__ __launch_bounds__(256) void make_X(const float* __restrict__ in,
                                              unsigned short* __restrict__ X) {
    int rloc = threadIdx.x >> 6;
    int c8   = (threadIdx.x & 63) << 3;
    int row  = blockIdx.x * 4 + rloc;          // [0, 2052)
    int b    = blockIdx.y;
    if (row >= 2049) return;
    unsigned short* dst = X + ((size_t)b * 2049 + row) * 512 + c8;
    alignas(16) unsigned short hh[8];
    if (row == 0) {
#pragma unroll
        for (int r = 0; r < 8; ++r) hh[r] = 0;
    } else {
        const float* src = in + ((size_t)b * 2048 + row - 1) * 512 + c8;
        float4 a = *(const float4*)src;
        float4 v = *(const float4*)(src + 4);
        hh[0] = f2bf(a.x); hh[1] = f2bf(a.y); hh[2] = f2bf(a.z); hh[3] = f2bf(a.w);
        hh[4] = f2bf(v.x); hh[5] = f2bf(v.y); hh[6] = f2bf(v.z); hh[7] = f2bf(v.w);
    }
    *(int4*)dst = *(const int4*)hh;
}

// ---------------------------------------------------------------------------
// K1: B bf16 [N][1024]: Bt[o][kc*512 + d] = w[o*1024 + d*2 + kc]
__global__ __launch_bounds__(256) void make_B(const float* __restrict__ w,
                                              unsigned short* __restrict__ Bt) {
    int i = blockIdx.x * 256 + threadIdx.x;     // 786432
    int o = i >> 9, d = i & 511;
    float w0 = w[(size_t)(o * 512 + d) * 2];
    float w1 = w[(size_t)(o * 512 + d) * 2 + 1];
    Bt[(size_t)o * 1024 + d]       = f2bf(w0);
    Bt[(size_t)o * 1024 + 512 + d] = f2bf(w1);
}

// ---------------------------------------------------------------------------
// K2: GEMM -> GT[n][m] (bf16, pre-activation, +bias).
// A row m = Xpad[b] + t*512 .. +1024 (contiguous, overlapping rows).
// 128x128 tile, BK=32, 4 waves x 4x4 16x16x32 bf16 MFMA, global_load_lds,
// XOR swizzle folded into the global address; XCD-aware block swizzle.
__global__ __launch_bounds__(256) void gemm_gates(const unsigned short* __restrict__ X,
                                                  const unsigned short* __restrict__ B,
                                                  const float* __restrict__ bias,
                                                  unsigned short* __restrict__ GT) {
    __shared__ int4 sA[512];
    __shared__ int4 sB[512];

    const int tid = threadIdx.x;
    const int bx  = blockIdx.x;
    const int xcd = bx & 7;
    const int i2  = bx >> 3;               // [0,384)
    const int mT  = xcd * 32 + i2 / 12;
    const int nT  = i2 % 12;
    const int m0  = mT * 128, n0 = nT * 128;
    const int b0  = m0 >> 11;              // tile is fully inside one batch
    const int t0  = m0 & 2047;

    const int mloc = tid >> 2;
    const int qsw  = (tid & 3) ^ ((mloc >> 1) & 3);
    const unsigned short* ga0 =
        X + ((size_t)b0 * 2049 + t0 + mloc) * 512 + qsw * 8;
    const unsigned short* ga1 = ga0 + (size_t)64 * 512;
    const unsigned short* gb0 = B + (size_t)(n0 + mloc) * 1024 + qsw * 8;
    const unsigned short* gb1 = B + (size_t)(n0 + 64 + mloc) * 1024 + qsw * 8;

    char* la0 = (char*)sA + tid * 16;
    char* la1 = (char*)sA + 4096 + tid * 16;
    char* lb0 = (char*)sB + tid * 16;
    char* lb1 = (char*)sB + 4096 + tid * 16;

    const int lane = tid & 63;
    const int wv   = tid >> 6;
    const int wm   = (wv & 1) * 64, wn = (wv >> 1) * 64;
    const int lr   = lane & 15, lq = lane >> 4;

    int sAidx[4], sBidx[4];
#pragma unroll
    for (int i = 0; i < 4; ++i) {
        int mi = wm + 16 * i + lr;
        sAidx[i] = mi * 4 + (lq ^ ((mi >> 1) & 3));
        int ni = wn + 16 * i + lr;
        sBidx[i] = ni * 4 + (lq ^ ((ni >> 1) & 3));
    }

    f32x4 acc[4][4] = {};

    for (int kt = 0; kt < KTOT; kt += 32) {
        __builtin_amdgcn_global_load_lds(
            (__attribute__((address_space(1))) void*)(void*)ga0,
            (__attribute__((address_space(3))) void*)la0, 16, 0, 0);
        __builtin_amdgcn_global_load_lds(
            (__attribute__((address_space(1))) void*)(void*)ga1,
            (__attribute__((address_space(3))) void*)la1, 16, 0, 0);
        __builtin_amdgcn_global_load_lds(
            (__attribute__((address_space(1))) void*)(void*)gb0,
            (__attribute__((address_space(3))) void*)lb0, 16, 0, 0);
        __builtin_amdgcn_global_load_lds(
            (__attribute__((address_space(1))) void*)(void*)gb1,
            (__attribute__((address_space(3))) void*)lb1, 16, 0, 0);
        ga0 += 32; ga1 += 32; gb0 += 32; gb1 += 32;
        __syncthreads();

        bf16x8 af[4], bfr[4];
#pragma unroll
        for (int i = 0; i < 4; ++i) af[i]  = __builtin_bit_cast(bf16x8, sA[sAidx[i]]);
#pragma unroll
        for (int j = 0; j < 4; ++j) bfr[j] = __builtin_bit_cast(bf16x8, sB[sBidx[j]]);

#pragma unroll
        for (int i = 0; i < 4; ++i)
#pragma unroll
            for (int j = 0; j < 4; ++j)
                acc[i][j] = __builtin_amdgcn_mfma_f32_16x16x32_bf16(af[i], bfr[j],
                                                                    acc[i][j], 0, 0, 0);
        __syncthreads();
    }

    // epilogue: C/D layout col=lane&15, row=(lane>>4)*4+r; transposed 8B stores
#pragma unroll
    for (int j = 0; j < 4; ++j) {
        int gn = n0 + wn + 16 * j + lr;
        float bj = bias[gn];
#pragma unroll
        for (int i = 0; i < 4; ++i) {
            int rowb = m0 + wm + 16 * i + lq * 4;
            alignas(8) unsigned short pk[4];
#pragma unroll
            for (int r = 0; r < 4; ++r) pk[r] = f2bf(acc[i][j][r] + bj);
            *(int2*)(GT + (size_t)gn * MTOT + rowb) = *(const int2*)pk;
        }
    }
}

// ---------------------------------------------------------------------------
// K3a: per-chunk aggregates, idx = b*16384 + s*512 + h.
// Full-chunk register burst: 8 int4 loads/stream back-to-back -> every fetched
// 128B line fully consumed while resident.
__global__ __launch_bounds__(256) void scan_agg(const unsigned short* __restrict__ GT,
                                                float* __restrict__ P,
                                                float* __restrict__ C) {
    int idx = blockIdx.x * 256 + threadIdx.x;    // [0, 16*32*512)
    int h = idx & 511, s = (idx >> 9) & 31, b = idx >> 14;
    const unsigned short* gz = GT + (size_t)h * MTOT + (size_t)b * TLEN + (size_t)s * LC;
    const unsigned short* gf = gz + (size_t)DCH * MTOT;

    int4 rz[8], rf[8];
#pragma unroll
    for (int q = 0; q < 8; ++q) rz[q] = *(const int4*)(gz + 8 * q);
#pragma unroll
    for (int q = 0; q < 8; ++q) rf[q] = *(const int4*)(gf + 8 * q);

    float p = 1.f, c = 0.f;
#pragma unroll
    for (int q = 0; q < 8; ++q) {
        bf16x8 zv = __builtin_bit_cast(bf16x8, rz[q]);
        bf16x8 fv = __builtin_bit_cast(bf16x8, rf[q]);
#pragma unroll
        for (int r = 0; r < 8; ++r) {
            float f = sigmoidf_((float)fv[r]);
            float z = 2.f * sigmoidf_(2.f * (float)zv[r]) - 1.f;   // tanh
            c = f * c + (1.f - f) * z;
            p *= f;
        }
    }
    P[idx] = p;
    C[idx] = c;
}

// ---------------------------------------------------------------------------
// K3b: exclusive scan over SC=32 chunks per (b,h) chain. 8192 threads.
__global__ __launch_bounds__(256) void scan_chunks(const float* __restrict__ P,
                                                   const float* __restrict__ C,
                                                   float* __restrict__ I) {
    int j = blockIdx.x * 256 + threadIdx.x;      // [0, 8192)
    int b = j >> 9, h = j & 511;
    size_t base = (size_t)b * (SC * DCH) + h;
    float cc = 0.f;
#pragma unroll
    for (int s = 0; s < SC; ++s) {
        size_t o = base + (size_t)s * DCH;
        I[o] = cc;
        cc = P[o] * cc + C[o];
    }
}

// ---------------------------------------------------------------------------
// K3c: apply. Block = (b, s); thread covers 2 h -> float2 stores (512B/wave).
// Half-chunk register bursts: 6 streams x 4 int4 = 96 VGPR live.
__global__ __launch_bounds__(256) void scan_apply(const unsigned short* __restrict__ GT,
                                                  const float* __restrict__ I,
                                                  float* __restrict__ out) {
    const int tid = threadIdx.x;
    const int s = blockIdx.x & 31;
    const int b = blockIdx.x >> 5;
    const int h = tid << 1;
    const size_t mb = (size_t)b * TLEN + (size_t)s * LC;

    const unsigned short* gz0 = GT + (size_t)h * MTOT + mb;
    const unsigned short* gz1 = gz0 + MTOT;
    const unsigned short* gf0 = gz0 + (size_t)DCH * MTOT;
    const unsigned short* gf1 = gf0 + MTOT;
    const unsigned short* go0 = gz0 + (size_t)(2 * DCH) * MTOT;
    const unsigned short* go1 = go0 + MTOT;

    const size_t BTH = (size_t)NB * TLEN * DCH;
    float* oC  = out + mb * DCH + h;
    float* oOC = oC + BTH;

    size_t ib = (size_t)b * (SC * DCH) + (size_t)s * DCH + h;
    float c0 = I[ib], c1 = I[ib + 1];

#pragma unroll
    for (int half = 0; half < 2; ++half) {
        const int k0 = half * 32;
        int4 rz0[4], rz1[4], rf0[4], rf1[4], ro0[4], ro1[4];
#pragma unroll
        for (int q = 0; q < 4; ++q) rz0[q] = *(const int4*)(gz0 + k0 + 8 * q);
#pragma unroll
        for (int q = 0; q < 4; ++q) rz1[q] = *(const int4*)(gz1 + k0 + 8 * q);
#pragma unroll
        for (int q = 0; q < 4; ++q) rf0[q] = *(const int4*)(gf0 + k0 + 8 * q);
#pragma unroll
        for (int q = 0; q < 4; ++q) rf1[q] = *(const int4*)(gf1 + k0 + 8 * q);
#pragma unroll
        for (int q = 0; q < 4; ++q) ro0[q] = *(const int4*)(go0 + k0 + 8 * q);
#pragma unroll
        for (int q = 0; q < 4; ++q) ro1[q] = *(const int4*)(go1 + k0 + 8 * q);

#pragma unroll
        for (int q = 0; q < 4; ++q) {
            bf16x8 zv0 = __builtin_bit_cast(bf16x8, rz0[q]);
            bf16x8 zv1 = __builtin_bit_cast(bf16x8, rz1[q]);
            bf16x8 fv0 = __builtin_bit_cast(bf16x8, rf0[q]);
            bf16x8 fv1 = __builtin_bit_cast(bf16x8, rf1[q]);
            bf16x8 ov0 = __builtin_bit_cast(bf16x8, ro0[q]);
            bf16x8 ov1 = __builtin_bit_cast(bf16x8, ro1[q]);
#pragma unroll
            for (int r = 0; r < 8; ++r) {
                float f0 = sigmoidf_((float)fv0[r]);
                float f1 = sigmoidf_((float)fv1[r]);
                float z0 = 2.f * sigmoidf_(2.f * (float)zv0[r]) - 1.f;
                float z1 = 2.f * sigmoidf_(2.f * (float)zv1[r]) - 1.f;
                float o0 = sigmoidf_((float)ov0[r]);
                float o1 = sigmoidf_((float)ov1[r]);
                c0 = f0 * c0 + (1.f - f0) * z0;
                c1 = f1 * c1 + (1.f - f1) * z1;
                size_t off = (size_t)(k0 + q * 8 + r) * DCH;
                float2 cc; cc.x = c0; cc.y = c1;
                *(float2*)(oC + off) = cc;
                float2 oc; oc.x = o0 * c0; oc.y = o1 * c1;
                *(float2*)(oOC + off) = oc;
            }
        }
    }
}

// ---------------------------------------------------------------------------
extern "C" void kernel_launch(void* const* d_in, const int* in_sizes, int n_in,
                              void* d_out, int out_size, void* d_ws, size_t ws_size,
                              hipStream_t stream) {
    const float* in   = (const float*)d_in[0];   // [16,2048,512] f32
    const float* w    = (const float*)d_in[1];   // [1536,512,2] f32
    const float* bias = (const float*)d_in[2];   // [1536] f32
    float* out = (float*)d_out;                  // [2][16,2048,512] f32

    unsigned short* Xpad = (unsigned short*)d_ws;                       // 33.6 MB
    unsigned short* Bbf  = Xpad + (size_t)NB * 2049 * 512;
    unsigned short* GT   = Bbf + (size_t)NTOT * 1024;

    // scan temporaries overlay the (dead-after-gemm) Xpad region: 3 x 1 MB f32
    float* P = (float*)d_ws;
    float* C = P + (size_t)NB * SC * DCH;
    float* I = C + (size_t)NB * SC * DCH;

    make_X<<<dim3(513, 16), dim3(256), 0, stream>>>(in, Xpad);
    make_B<<<dim3(3072), dim3(256), 0, stream>>>(w, Bbf);
    gemm_gates<<<dim3(3072), dim3(256), 0, stream>>>(Xpad, Bbf, bias, GT);
    scan_agg<<<dim3(1024), dim3(256), 0, stream>>>(GT, P, C);
    scan_chunks<<<dim3(32), dim3(256), 0, stream>>>(P, C, I);
    scan_apply<<<dim3(512), dim3(256), 0, stream>>>(GT, I, out);
}